// Round 1
// baseline (40081.708 us; speedup 1.0000x reference)
//
#include <hip/hip_runtime.h>
#include <hip/hip_bf16.h>

// TrueMarkovChain: s_t = Wt3·silu(Wt2·silu(Wt1·[s_{t-1}, x_t])) recurrence.
// v1: bf16 MFMA, xc-hoist of the x-half of Wt1 (stored inside d_out),
// persistent 128-WG kernel with per-row-block flag sync.

#define B_ 128
#define L_ 512
#define DI 1024
#define DS 1024

typedef __bf16 v8bf __attribute__((ext_vector_type(8)));
typedef float f32x4 __attribute__((ext_vector_type(4)));

__device__ inline f32x4 mfma16(v8bf a, v8bf b, f32x4 c) {
  return __builtin_amdgcn_mfma_f32_16x16x32_bf16(a, b, c, 0, 0, 0);
}

__device__ inline float silu_f(float x) { return x / (1.f + __expf(-x)); }

__device__ inline v8bf cvt8(float4 a, float4 b) {
  v8bf v;
  v[0] = (__bf16)a.x; v[1] = (__bf16)a.y; v[2] = (__bf16)a.z; v[3] = (__bf16)a.w;
  v[4] = (__bf16)b.x; v[5] = (__bf16)b.y; v[6] = (__bf16)b.z; v[7] = (__bf16)b.w;
  return v;
}

// ---------------- fp32 -> bf16 strided converter (8 elems/thread) ------------
__global__ void cvt_kernel(const float* __restrict__ src, __bf16* __restrict__ dst,
                           int total8, int log2cols, int sstride, int soff) {
  int i = blockIdx.x * 256 + threadIdx.x;
  if (i >= total8) return;
  long long e = (long long)i * 8;
  int r = (int)(e >> log2cols);
  int c = (int)(e & ((1LL << log2cols) - 1));
  const float* s = src + (size_t)r * sstride + soff + c;
  float4 f0 = *(const float4*)(s);
  float4 f1 = *(const float4*)(s + 4);
  *(v8bf*)(dst + e) = cvt8(f0, f1);
}

// ---------------- xc[t] = x_t @ Wt1_x^T + bt1 (parallel hoist) ---------------
// Stored bf16 into d_out: xc[t][b][n] at ((b*512 + t)*2048 + n) bf16 elems.
__global__ __launch_bounds__(512, 1) void xc_gemm_kernel(
    const float* __restrict__ past, const __bf16* __restrict__ w1x,
    const float* __restrict__ bt1, __bf16* __restrict__ xc) {
  const int t = blockIdx.y + 1;          // 1..511
  const int nb = blockIdx.x;             // 0..3
  const int tid = threadIdx.x, wid = tid >> 6, lane = tid & 63;
  const int wm = wid >> 1, wn = wid & 1; // waves 4x2
  const int m0 = wm * 32;
  const int n0 = nb * 512 + wn * 256;
  const int lr = lane & 15, lc = lane >> 4;

  f32x4 acc[2][16] = {};
  const float* a0p = past + ((size_t)(m0 + lr) * 512 + t) * 1024 + lc * 8;
  const float* a1p = a0p + (size_t)16 * 512 * 1024;
  const __bf16* bp = w1x + (size_t)(n0 + lr) * 1024 + lc * 8;

  for (int k = 0; k < 1024; k += 32) {
    float4 x00 = *(const float4*)(a0p + k);
    float4 x01 = *(const float4*)(a0p + k + 4);
    float4 x10 = *(const float4*)(a1p + k);
    float4 x11 = *(const float4*)(a1p + k + 4);
    v8bf a0 = cvt8(x00, x01), a1 = cvt8(x10, x11);
#pragma unroll
    for (int j = 0; j < 16; ++j) {
      v8bf b = *(const v8bf*)(bp + (size_t)j * 16 * 1024 + k);
      acc[0][j] = mfma16(a0, b, acc[0][j]);
      acc[1][j] = mfma16(a1, b, acc[1][j]);
    }
  }
  const int cm = (lane >> 4) << 2, cn = lane & 15;
#pragma unroll
  for (int f = 0; f < 2; ++f)
#pragma unroll
    for (int j = 0; j < 16; ++j) {
      int n = n0 + j * 16 + cn;
      float bias = bt1[n];
#pragma unroll
      for (int r = 0; r < 4; ++r) {
        int m = m0 + f * 16 + cm + r;
        xc[((size_t)m * 512 + t) * 2048 + n] = (__bf16)(acc[f][j][r] + bias);
      }
    }
}

// ---------------- flag sync helpers ------------------------------------------
__device__ inline void flag_add(unsigned* f) {
  __syncthreads();
  __threadfence();  // defensive: ensure all WG stores reach device scope
  if (threadIdx.x == 0)
    __hip_atomic_fetch_add(f, 1u, __ATOMIC_RELEASE, __HIP_MEMORY_SCOPE_AGENT);
}
__device__ inline void flag_wait(unsigned* f, unsigned target) {
  if (threadIdx.x == 0) {
    while (__hip_atomic_load(f, __ATOMIC_RELAXED, __HIP_MEMORY_SCOPE_AGENT) < target)
      __builtin_amdgcn_s_sleep(2);
    (void)__hip_atomic_load(f, __ATOMIC_ACQUIRE, __HIP_MEMORY_SCOPE_AGENT);
  }
  __syncthreads();
}

// 16x16 output fragment GEMM, K templated, direct-from-global fragments.
template <int K>
__device__ inline f32x4 frag_gemm(const __bf16* __restrict__ A, int lda,
                                  const __bf16* __restrict__ Wb, int ldb) {
  const int lane = threadIdx.x & 63;
  const __bf16* ap = A + (size_t)(lane & 15) * lda + ((lane >> 4) << 3);
  const __bf16* bp = Wb + (size_t)(lane & 15) * ldb + ((lane >> 4) << 3);
  f32x4 acc = {0.f, 0.f, 0.f, 0.f};
#pragma unroll 8
  for (int k = 0; k < K; k += 32) {
    v8bf a = *(const v8bf*)(ap + k);
    v8bf b = *(const v8bf*)(bp + k);
    acc = mfma16(a, b, acc);
  }
  return acc;
}

// ---------------- persistent recurrence kernel -------------------------------
// 128 WGs x 256 thr. WG w: mb = w>>5 (row block of 32 batch rows), col = w&31.
// Phase A: z1 = silu(s_prev @ Wt1s^T + xc[t])   tiles 32x64  (K=1024)
// Phase B: z2 = silu(z1 @ Wt2^T + bt2)          tiles 32x32  (K=2048)
// Phase C: s  = z2 @ Wt3^T + bt3 -> out fp32 + s_bf bf16     (K=1024)
__global__ __launch_bounds__(256, 1) void recurrent_kernel(
    const __bf16* __restrict__ wWi1, const __bf16* __restrict__ wWi2,
    const __bf16* __restrict__ wWt1s, const __bf16* __restrict__ wWt2,
    const __bf16* __restrict__ wWt3, const __bf16* __restrict__ x0bf,
    __bf16* __restrict__ sbf0, __bf16* __restrict__ sbf1,
    __bf16* __restrict__ z1b0, __bf16* __restrict__ z1b1,
    __bf16* __restrict__ z2b0, __bf16* __restrict__ z2b1,
    const float* __restrict__ bi1, const float* __restrict__ bi2,
    const float* __restrict__ bt2, const float* __restrict__ bt3,
    float* __restrict__ out, unsigned* __restrict__ flags) {
  const int w = blockIdx.x;
  const int mb = w >> 5, col = w & 31;
  const int tid = threadIdx.x, wid = tid >> 6, lane = tid & 63;
  const int wm = wid >> 1, wn = wid & 1;
  const int cm = (lane >> 4) << 2, cn = lane & 15;
  unsigned* fA = flags + mb * 32;
  unsigned* fB = flags + 128 + mb * 32;
  unsigned* fC = flags + 256 + mb * 32;
  const int m_off = mb * 32 + wm * 16;

  // ---- B0: h0 = silu(x0 @ Wi1^T + bi1) -> z2b0
  {
    const int n_off = col * 32 + wn * 16;
    f32x4 acc = frag_gemm<1024>(x0bf + (size_t)m_off * 1024, 1024,
                                wWi1 + (size_t)n_off * 1024, 1024);
#pragma unroll
    for (int r = 0; r < 4; ++r) {
      int m = m_off + cm + r, n = n_off + cn;
      z2b0[(size_t)m * 1024 + n] = (__bf16)silu_f(acc[r] + bi1[n]);
    }
    flag_add(fB);
  }
  // ---- C0: s0 = h0 @ Wi2^T + bi2 -> out[:,0,:] + sbf0
  flag_wait(fB, 32u);
  {
    const int n_off = col * 32 + wn * 16;
    f32x4 acc = frag_gemm<1024>(z2b0 + (size_t)m_off * 1024, 1024,
                                wWi2 + (size_t)n_off * 1024, 1024);
#pragma unroll
    for (int r = 0; r < 4; ++r) {
      int m = m_off + cm + r, n = n_off + cn;
      float v = acc[r] + bi2[n];
      out[(size_t)m * 524288 + n] = v;
      sbf0[(size_t)m * 1024 + n] = (__bf16)v;
    }
    flag_add(fC);
  }

  const __bf16* xc = (const __bf16*)out;
  for (int t = 1; t < 512; ++t) {
    const int p = t & 1;
    const __bf16* sprev = p ? sbf0 : sbf1;
    __bf16* scur = p ? sbf1 : sbf0;
    __bf16* z1p = p ? z1b1 : z1b0;
    __bf16* z2p = p ? z2b1 : z2b0;

    flag_wait(fC, 32u * (unsigned)t);
    { // phase A (tile 32x64; wave computes 16x32 = two frags)
      const int n_base = col * 64 + wn * 32;
      const __bf16* ap = sprev + (size_t)(m_off + (lane & 15)) * 1024 + ((lane >> 4) << 3);
      const __bf16* bp0 = wWt1s + (size_t)(n_base + (lane & 15)) * 1024 + ((lane >> 4) << 3);
      const __bf16* bp1 = bp0 + (size_t)16 * 1024;
      f32x4 acc0 = {0.f, 0.f, 0.f, 0.f}, acc1 = {0.f, 0.f, 0.f, 0.f};
#pragma unroll 8
      for (int k = 0; k < 1024; k += 32) {
        v8bf a = *(const v8bf*)(ap + k);
        v8bf b0 = *(const v8bf*)(bp0 + k);
        v8bf b1 = *(const v8bf*)(bp1 + k);
        acc0 = mfma16(a, b0, acc0);
        acc1 = mfma16(a, b1, acc1);
      }
#pragma unroll
      for (int f = 0; f < 2; ++f) {
        int n = n_base + f * 16 + cn;
#pragma unroll
        for (int r = 0; r < 4; ++r) {
          int m = m_off + cm + r;
          float v = (f ? acc1[r] : acc0[r]) +
                    (float)xc[((size_t)m * 512 + (size_t)t) * 2048 + n];
          z1p[(size_t)m * 2048 + n] = (__bf16)silu_f(v);
        }
      }
      flag_add(fA);
    }
    flag_wait(fA, 32u * (unsigned)t);
    { // phase B
      const int n_off = col * 32 + wn * 16;
      f32x4 acc = frag_gemm<2048>(z1p + (size_t)m_off * 2048, 2048,
                                  wWt2 + (size_t)n_off * 2048, 2048);
#pragma unroll
      for (int r = 0; r < 4; ++r) {
        int m = m_off + cm + r, n = n_off + cn;
        z2p[(size_t)m * 1024 + n] = (__bf16)silu_f(acc[r] + bt2[n]);
      }
      flag_add(fB);
    }
    flag_wait(fB, 32u * (unsigned)(t + 1));
    { // phase C
      const int n_off = col * 32 + wn * 16;
      f32x4 acc = frag_gemm<1024>(z2p + (size_t)m_off * 1024, 1024,
                                  wWt3 + (size_t)n_off * 1024, 1024);
#pragma unroll
      for (int r = 0; r < 4; ++r) {
        int m = m_off + cm + r, n = n_off + cn;
        float v = acc[r] + bt3[n];
        out[(size_t)m * 524288 + (size_t)t * 1024 + n] = v;
        scur[(size_t)m * 1024 + n] = (__bf16)v;
      }
      flag_add(fC);
    }
  }
}

// ---------------- host launcher ----------------------------------------------
extern "C" void kernel_launch(void* const* d_in, const int* in_sizes, int n_in,
                              void* d_out, int out_size, void* d_ws, size_t ws_size,
                              hipStream_t stream) {
  (void)in_sizes; (void)n_in; (void)out_size; (void)ws_size;
  const float* past = (const float*)d_in[0];
  const float* Wi1 = (const float*)d_in[1];
  const float* bi1 = (const float*)d_in[2];
  const float* Wi2 = (const float*)d_in[3];
  const float* bi2 = (const float*)d_in[4];
  const float* Wt1 = (const float*)d_in[5];
  const float* bt1 = (const float*)d_in[6];
  const float* Wt2 = (const float*)d_in[7];
  const float* bt2 = (const float*)d_in[8];
  const float* Wt3 = (const float*)d_in[9];
  const float* bt3 = (const float*)d_in[10];
  float* out = (float*)d_out;

  char* ws = (char*)d_ws;
  size_t off = 0;
  unsigned* flags = (unsigned*)(ws + off); off += 4096;
  __bf16* wWi1 = (__bf16*)(ws + off);  off += (size_t)1024 * 1024 * 2;
  __bf16* wWi2 = (__bf16*)(ws + off);  off += (size_t)1024 * 1024 * 2;
  __bf16* wWt1s = (__bf16*)(ws + off); off += (size_t)2048 * 1024 * 2;
  __bf16* wWt1x = (__bf16*)(ws + off); off += (size_t)2048 * 1024 * 2;
  __bf16* wWt2 = (__bf16*)(ws + off);  off += (size_t)1024 * 2048 * 2;
  __bf16* wWt3 = (__bf16*)(ws + off);  off += (size_t)1024 * 1024 * 2;
  __bf16* x0bf = (__bf16*)(ws + off);  off += (size_t)128 * 1024 * 2;
  __bf16* sbf0 = (__bf16*)(ws + off);  off += (size_t)128 * 1024 * 2;
  __bf16* sbf1 = (__bf16*)(ws + off);  off += (size_t)128 * 1024 * 2;
  __bf16* z1b0 = (__bf16*)(ws + off);  off += (size_t)128 * 2048 * 2;
  __bf16* z1b1 = (__bf16*)(ws + off);  off += (size_t)128 * 2048 * 2;
  __bf16* z2b0 = (__bf16*)(ws + off);  off += (size_t)128 * 1024 * 2;
  __bf16* z2b1 = (__bf16*)(ws + off);  off += (size_t)128 * 1024 * 2;

  hipMemsetAsync(flags, 0, 4096, stream);

  auto cvt = [&](const float* s, __bf16* d, int rows, int cols, int log2c,
                 int sstride, int soff) {
    int total8 = rows * cols / 8;
    hipLaunchKernelGGL(cvt_kernel, dim3((total8 + 255) / 256), dim3(256), 0,
                       stream, s, d, total8, log2c, sstride, soff);
  };
  cvt(Wi1, wWi1, 1024, 1024, 10, 1024, 0);
  cvt(Wi2, wWi2, 1024, 1024, 10, 1024, 0);
  cvt(Wt1, wWt1s, 2048, 1024, 10, 2048, 0);
  cvt(Wt1, wWt1x, 2048, 1024, 10, 2048, 1024);
  cvt(Wt2, wWt2, 1024, 2048, 11, 2048, 0);
  cvt(Wt3, wWt3, 1024, 1024, 10, 1024, 0);
  cvt(past, x0bf, 128, 1024, 10, 512 * 1024, 0);

  hipLaunchKernelGGL(xc_gemm_kernel, dim3(4, 511), dim3(512), 0, stream,
                     past, wWt1x, bt1, (__bf16*)d_out);

  hipLaunchKernelGGL(recurrent_kernel, dim3(128), dim3(256), 0, stream,
                     wWi1, wWi2, wWt1s, wWt2, wWt3, x0bf,
                     sbf0, sbf1, z1b0, z1b1, z2b0, z2b1,
                     bi1, bi2, bt2, bt3, out, flags);
}

// Round 2
// 24781.525 us; speedup vs baseline: 1.6174x; 1.6174x over previous
//
#include <hip/hip_runtime.h>
#include <hip/hip_bf16.h>

// TrueMarkovChain v2: phase-specialized persistent kernel.
//  - Roles: A (64 WGs): z1 = silu(s_prev @ Wt1s^T + xc_t)   [K=1024, n-slice 32]
//           B (64 WGs): z2 = silu(z1 @ Wt2^T + bt2)         [K=2048, n-slice 16]
//           C (32 WGs): s  = z2 @ Wt3^T + bt3 -> out, sbf   [K=1024, n-slice 32]
//           X (96 WGs): xc[t] = x_t @ Wt1x^T + bt1 (parallel, per-t flags)
//  - Each A/B/C WG stages its weight slice into LDS ONCE (64KB max).
//  - Single-writer release-store flags; 64-lane parallel polling.
//  - Activation K-loops use a PF=16 prefetch ring (deep ILP for L3 latency).

typedef __bf16 v8bf __attribute__((ext_vector_type(8)));
typedef float f32x4 __attribute__((ext_vector_type(4)));

__device__ inline f32x4 mfma16(v8bf a, v8bf b, f32x4 c) {
  return __builtin_amdgcn_mfma_f32_16x16x32_bf16(a, b, c, 0, 0, 0);
}
__device__ inline float silu_f(float x) { return x / (1.f + __expf(-x)); }

__device__ inline v8bf cvt8(float4 a, float4 b) {
  v8bf v;
  v[0] = (__bf16)a.x; v[1] = (__bf16)a.y; v[2] = (__bf16)a.z; v[3] = (__bf16)a.w;
  v[4] = (__bf16)b.x; v[5] = (__bf16)b.y; v[6] = (__bf16)b.z; v[7] = (__bf16)b.w;
  return v;
}

// ---------------- fp32 -> bf16 strided converter (8 elems/thread) ------------
__global__ void cvt_kernel(const float* __restrict__ src, __bf16* __restrict__ dst,
                           int total8, int log2cols, int sstride, int soff) {
  int i = blockIdx.x * 256 + threadIdx.x;
  if (i >= total8) return;
  long long e = (long long)i * 8;
  int r = (int)(e >> log2cols);
  int c = (int)(e & ((1LL << log2cols) - 1));
  const float* s = src + (size_t)r * sstride + soff + c;
  float4 f0 = *(const float4*)(s);
  float4 f1 = *(const float4*)(s + 4);
  *(v8bf*)(dst + e) = cvt8(f0, f1);
}

// ---------------- sync primitives --------------------------------------------
__device__ inline void flag_set(unsigned* f, unsigned v) {
  __syncthreads();  // all WG writes drained to L2 (vmcnt0 before barrier)
  if (threadIdx.x == 0) {
    __threadfence();
    __hip_atomic_store(f, v, __ATOMIC_RELEASE, __HIP_MEMORY_SCOPE_AGENT);
  }
}
__device__ inline void flags_wait(const unsigned* f, int n, unsigned target) {
  if (threadIdx.x < 64) {
    const int lane = threadIdx.x;
    const unsigned* p = f + (lane < n ? lane : 0);
    while (__hip_atomic_load(p, __ATOMIC_RELAXED, __HIP_MEMORY_SCOPE_AGENT) < target)
      __builtin_amdgcn_s_sleep(1);
    (void)__hip_atomic_load(f, __ATOMIC_ACQUIRE, __HIP_MEMORY_SCOPE_AGENT);
  }
  __syncthreads();
}
// A waits: fC[0..31] >= t  AND  fX[t] >= 1
__device__ inline void wait_A(const unsigned* fC, const unsigned* fXt, unsigned t) {
  if (threadIdx.x < 64) {
    const int lane = threadIdx.x;
    const unsigned* p = (lane < 32) ? (fC + lane) : fXt;
    const unsigned tgt = (lane < 32) ? t : 1u;
    while (__hip_atomic_load(p, __ATOMIC_RELAXED, __HIP_MEMORY_SCOPE_AGENT) < tgt)
      __builtin_amdgcn_s_sleep(1);
    (void)__hip_atomic_load(fC, __ATOMIC_ACQUIRE, __HIP_MEMORY_SCOPE_AGENT);
  }
  __syncthreads();
}

// ---------------- weight staging into LDS [K/8][NR][8] -----------------------
template <int K, int NR>
__device__ inline void stage_w(const __bf16* __restrict__ wg, __bf16* wl, int tid) {
  constexpr int TOT = (K / 8) * NR;
#pragma unroll
  for (int idx = tid; idx < TOT; idx += 256) {
    const int kb = idx / NR, n = idx % NR;
    *(v8bf*)(wl + (size_t)idx * 8) = *(const v8bf*)(wg + (size_t)n * K + kb * 8);
  }
}

// ---------------- LDS-weight GEMM, PF-deep activation prefetch ring ----------
// act points at this wave's 32-row block (row-major, stride ldk = K).
// acc[mf][f]: mf = M-frag (rows +0/+16), f = N-frag.
template <int KITERS, int NF, int PF>
__device__ inline void lds_gemm(const __bf16* act, int ldk, const __bf16* wl,
                                int lane, f32x4 (&acc)[2][NF]) {
  const int lr = lane & 15, lc = lane >> 4;
  const __bf16* a0 = act + (size_t)lr * ldk + lc * 8;
  const __bf16* a1 = a0 + (size_t)16 * ldk;
  const __bf16* bl = wl + lr * 8;
  v8bf ab0[PF], ab1[PF];
#pragma unroll
  for (int i = 0; i < PF; ++i) {
    ab0[i] = *(const v8bf*)(a0 + i * 32);
    ab1[i] = *(const v8bf*)(a1 + i * 32);
  }
#pragma unroll
  for (int it = 0; it < KITERS; ++it) {
    v8bf av0 = ab0[it % PF], av1 = ab1[it % PF];
    if (it + PF < KITERS) {
      ab0[it % PF] = *(const v8bf*)(a0 + (it + PF) * 32);
      ab1[it % PF] = *(const v8bf*)(a1 + (it + PF) * 32);
    }
#pragma unroll
    for (int f = 0; f < NF; ++f) {
      v8bf b = *(const v8bf*)(bl + (4 * it + lc) * (NF * 128) + f * 128);
      acc[0][f] = mfma16(av0, b, acc[0][f]);
      acc[1][f] = mfma16(av1, b, acc[1][f]);
    }
  }
}

// ---------------- global-weight GEMM (init phases only) ----------------------
template <int KITERS, int NF>
__device__ inline void glb_gemm(const __bf16* act, const __bf16* wg,
                                int lane, f32x4 (&acc)[2][NF]) {
  const int ldk = KITERS * 32;
  const int lr = lane & 15, lc = lane >> 4;
  const __bf16* a0 = act + (size_t)lr * ldk + lc * 8;
  const __bf16* a1 = a0 + (size_t)16 * ldk;
  const __bf16* bp = wg + (size_t)lr * ldk + lc * 8;
#pragma unroll 8
  for (int it = 0; it < KITERS; ++it) {
    v8bf av0 = *(const v8bf*)(a0 + it * 32);
    v8bf av1 = *(const v8bf*)(a1 + it * 32);
#pragma unroll
    for (int f = 0; f < NF; ++f) {
      v8bf b = *(const v8bf*)(bp + (size_t)f * 16 * ldk + it * 32);
      acc[0][f] = mfma16(av0, b, acc[0][f]);
      acc[1][f] = mfma16(av1, b, acc[1][f]);
    }
  }
}

// ---------------- persistent kernel ------------------------------------------
__global__ __launch_bounds__(256, 1) void recurrent_kernel(
    const __bf16* __restrict__ wWi1, const __bf16* __restrict__ wWi2,
    const __bf16* __restrict__ wWt1s, const __bf16* __restrict__ wWt2,
    const __bf16* __restrict__ wWt3, const __bf16* __restrict__ wWt1x,
    const __bf16* __restrict__ x0bf, const float* __restrict__ past,
    __bf16* sbf, __bf16* z1, __bf16* z2,
    const float* __restrict__ bi1, const float* __restrict__ bi2,
    const float* __restrict__ bt1, const float* __restrict__ bt2,
    const float* __restrict__ bt3,
    float* out, unsigned* flags) {
  __shared__ alignas(16) __bf16 wl[32768];  // 64 KB weight slice
  const int w = blockIdx.x;
  const int tid = threadIdx.x, wid = tid >> 6, lane = tid & 63;
  const int cm = (lane >> 4) << 2, cn = lane & 15;
  const int m_w = wid * 32;  // wave's 32-row block of M=128
  unsigned* fA = flags;
  unsigned* fB = flags + 64;
  unsigned* fC = flags + 128;
  unsigned* fX = flags + 192;  // fX[t], t=1..511
  const __bf16* xc = (const __bf16*)out;  // aliases out (bf16 view, slice t)

  if (w < 64) {
    // ================= A role =================
    const int n0 = w * 32;
    stage_w<1024, 32>(wWt1s + (size_t)n0 * 1024, wl, tid);
    __syncthreads();
    for (int t = 1; t < 512; ++t) {
      wait_A(fC, fX + t, (unsigned)t);
      // hoist xc loads (ready per fX[t]); latency hides under the gemm
      float xcv[2][2][4];
#pragma unroll
      for (int mf = 0; mf < 2; ++mf)
#pragma unroll
        for (int f = 0; f < 2; ++f)
#pragma unroll
          for (int r = 0; r < 4; ++r)
            xcv[mf][f][r] = (float)xc[((size_t)(m_w + mf * 16 + cm + r) * 512 + t) * 2048 +
                                      (n0 + f * 16 + cn)];
      f32x4 acc[2][2] = {};
      lds_gemm<32, 2, 16>(sbf + (size_t)m_w * 1024, 1024, wl, lane, acc);
#pragma unroll
      for (int mf = 0; mf < 2; ++mf)
#pragma unroll
        for (int f = 0; f < 2; ++f)
#pragma unroll
          for (int r = 0; r < 4; ++r) {
            int m = m_w + mf * 16 + cm + r, n = n0 + f * 16 + cn;
            z1[(size_t)m * 2048 + n] = (__bf16)silu_f(acc[mf][f][r] + xcv[mf][f][r]);
          }
      flag_set(fA + w, (unsigned)t);
    }
  } else if (w < 128) {
    // ================= B role =================
    const int b = w - 64;
    const int n0 = b * 16;
    stage_w<2048, 16>(wWt2 + (size_t)n0 * 2048, wl, tid);
    __syncthreads();
    {  // init: h0 = silu(x0 @ Wi1^T + bi1) -> z2
      const float biasI = bi1[n0 + cn];
      f32x4 acc[2][1] = {};
      glb_gemm<32, 1>(x0bf + (size_t)m_w * 1024, wWi1 + (size_t)n0 * 1024, lane, acc);
#pragma unroll
      for (int mf = 0; mf < 2; ++mf)
#pragma unroll
        for (int r = 0; r < 4; ++r) {
          int m = m_w + mf * 16 + cm + r;
          z2[(size_t)m * 1024 + (n0 + cn)] = (__bf16)silu_f(acc[mf][0][r] + biasI);
        }
      flag_set(fB + b, 1u);
    }
    const float biasB = bt2[n0 + cn];
    for (int t = 1; t < 512; ++t) {
      flags_wait(fA, 64, (unsigned)t);
      f32x4 acc[2][1] = {};
      lds_gemm<64, 1, 16>(z1 + (size_t)m_w * 2048, 2048, wl, lane, acc);
#pragma unroll
      for (int mf = 0; mf < 2; ++mf)
#pragma unroll
        for (int r = 0; r < 4; ++r) {
          int m = m_w + mf * 16 + cm + r;
          z2[(size_t)m * 1024 + (n0 + cn)] = (__bf16)silu_f(acc[mf][0][r] + biasB);
        }
      flag_set(fB + b, (unsigned)(t + 1));
    }
  } else if (w < 160) {
    // ================= C role =================
    const int c = w - 128;
    const int n0 = c * 32;
    stage_w<1024, 32>(wWt3 + (size_t)n0 * 1024, wl, tid);
    __syncthreads();
    {  // init: s0 = h0 @ Wi2^T + bi2 -> out[:,0,:], sbf
      float bI[2] = {bi2[n0 + cn], bi2[n0 + 16 + cn]};
      flags_wait(fB, 64, 1u);
      f32x4 acc[2][2] = {};
      glb_gemm<32, 2>(z2 + (size_t)m_w * 1024, wWi2 + (size_t)n0 * 1024, lane, acc);
#pragma unroll
      for (int mf = 0; mf < 2; ++mf)
#pragma unroll
        for (int f = 0; f < 2; ++f)
#pragma unroll
          for (int r = 0; r < 4; ++r) {
            int m = m_w + mf * 16 + cm + r, n = n0 + f * 16 + cn;
            float v = acc[mf][f][r] + bI[f];
            out[(size_t)m * 524288 + n] = v;
            sbf[(size_t)m * 1024 + n] = (__bf16)v;
          }
      flag_set(fC + c, 1u);
    }
    const float bC[2] = {bt3[n0 + cn], bt3[n0 + 16 + cn]};
    for (int t = 1; t < 512; ++t) {
      flags_wait(fB, 64, (unsigned)(t + 1));
      f32x4 acc[2][2] = {};
      lds_gemm<32, 2, 16>(z2 + (size_t)m_w * 1024, 1024, wl, lane, acc);
#pragma unroll
      for (int mf = 0; mf < 2; ++mf)
#pragma unroll
        for (int f = 0; f < 2; ++f)
#pragma unroll
          for (int r = 0; r < 4; ++r) {
            int m = m_w + mf * 16 + cm + r, n = n0 + f * 16 + cn;
            float v = acc[mf][f][r] + bC[f];
            out[(size_t)m * 524288 + (size_t)t * 1024 + n] = v;
            sbf[(size_t)m * 1024 + n] = (__bf16)v;
          }
      flag_set(fC + c, (unsigned)(t + 1));
    }
  } else {
    // ================= X role: xc[t] = x_t @ Wt1x^T + bt1 =================
    const int x = w - 160;
    const int lr = lane & 15, lc = lane >> 4;
    for (int t = 1 + x; t < 512; t += 96) {
      const float* ap0 = past + ((size_t)(m_w + lr) * 512 + t) * 1024 + lc * 8;
      const float* ap1 = ap0 + (size_t)16 * 512 * 1024;
      __bf16* xcw = (__bf16*)out;
      for (int nc = 0; nc < 2048; nc += 64) {
        const __bf16* bp = wWt1x + (size_t)(nc + lr) * 1024 + lc * 8;
        f32x4 acc[2][4] = {};
#pragma unroll 8
        for (int it = 0; it < 32; ++it) {
          float4 a00 = *(const float4*)(ap0 + it * 32);
          float4 a01 = *(const float4*)(ap0 + it * 32 + 4);
          float4 a10 = *(const float4*)(ap1 + it * 32);
          float4 a11 = *(const float4*)(ap1 + it * 32 + 4);
          v8bf av0 = cvt8(a00, a01), av1 = cvt8(a10, a11);
#pragma unroll
          for (int f = 0; f < 4; ++f) {
            v8bf b = *(const v8bf*)(bp + (size_t)f * 16 * 1024 + it * 32);
            acc[0][f] = mfma16(av0, b, acc[0][f]);
            acc[1][f] = mfma16(av1, b, acc[1][f]);
          }
        }
#pragma unroll
        for (int mf = 0; mf < 2; ++mf)
#pragma unroll
          for (int f = 0; f < 4; ++f)
#pragma unroll
            for (int r = 0; r < 4; ++r) {
              int m = m_w + mf * 16 + cm + r, n = nc + f * 16 + cn;
              xcw[((size_t)m * 512 + t) * 2048 + n] = (__bf16)(acc[mf][f][r] + bt1[n]);
            }
      }
      flag_set(fX + t, 1u);
    }
  }
}

// ---------------- host launcher ----------------------------------------------
extern "C" void kernel_launch(void* const* d_in, const int* in_sizes, int n_in,
                              void* d_out, int out_size, void* d_ws, size_t ws_size,
                              hipStream_t stream) {
  (void)in_sizes; (void)n_in; (void)out_size; (void)ws_size;
  const float* past = (const float*)d_in[0];
  const float* Wi1 = (const float*)d_in[1];
  const float* bi1 = (const float*)d_in[2];
  const float* Wi2 = (const float*)d_in[3];
  const float* bi2 = (const float*)d_in[4];
  const float* Wt1 = (const float*)d_in[5];
  const float* bt1 = (const float*)d_in[6];
  const float* Wt2 = (const float*)d_in[7];
  const float* bt2 = (const float*)d_in[8];
  const float* Wt3 = (const float*)d_in[9];
  const float* bt3 = (const float*)d_in[10];
  float* out = (float*)d_out;

  char* ws = (char*)d_ws;
  size_t off = 0;
  unsigned* flags = (unsigned*)(ws + off); off += 4096;
  __bf16* wWi1 = (__bf16*)(ws + off);  off += (size_t)1024 * 1024 * 2;
  __bf16* wWi2 = (__bf16*)(ws + off);  off += (size_t)1024 * 1024 * 2;
  __bf16* wWt1s = (__bf16*)(ws + off); off += (size_t)2048 * 1024 * 2;
  __bf16* wWt1x = (__bf16*)(ws + off); off += (size_t)2048 * 1024 * 2;
  __bf16* wWt2 = (__bf16*)(ws + off);  off += (size_t)1024 * 2048 * 2;
  __bf16* wWt3 = (__bf16*)(ws + off);  off += (size_t)1024 * 1024 * 2;
  __bf16* x0bf = (__bf16*)(ws + off);  off += (size_t)128 * 1024 * 2;
  __bf16* sbf = (__bf16*)(ws + off);   off += (size_t)128 * 1024 * 2;
  __bf16* z1 = (__bf16*)(ws + off);    off += (size_t)128 * 2048 * 2;
  __bf16* z2 = (__bf16*)(ws + off);    off += (size_t)128 * 1024 * 2;

  hipMemsetAsync(flags, 0, 4096, stream);

  auto cvt = [&](const float* s, __bf16* d, int rows, int cols, int log2c,
                 int sstride, int soff) {
    int total8 = rows * cols / 8;
    hipLaunchKernelGGL(cvt_kernel, dim3((total8 + 255) / 256), dim3(256), 0,
                       stream, s, d, total8, log2c, sstride, soff);
  };
  cvt(Wi1, wWi1, 1024, 1024, 10, 1024, 0);
  cvt(Wi2, wWi2, 1024, 1024, 10, 1024, 0);
  cvt(Wt1, wWt1s, 2048, 1024, 10, 2048, 0);
  cvt(Wt1, wWt1x, 2048, 1024, 10, 2048, 1024);
  cvt(Wt2, wWt2, 1024, 2048, 11, 2048, 0);
  cvt(Wt3, wWt3, 1024, 1024, 10, 1024, 0);
  cvt(past, x0bf, 128, 1024, 10, 512 * 1024, 0);

  hipLaunchKernelGGL(recurrent_kernel, dim3(256), dim3(256), 0, stream,
                     wWi1, wWi2, wWt1s, wWt2, wWt3, wWt1x, x0bf, past,
                     sbf, z1, z2, bi1, bi2, bt1, bt2, bt3, out, flags);
}